// Round 1
// baseline (175.553 us; speedup 1.0000x reference)
//
#include <hip/hip_runtime.h>
#include <math.h>
#include <float.h>

#define MAX_DET 25
#define IOU_THRES 0.7f
#define MAX_WH 7680.0f

__device__ __forceinline__ float sigm(float v) {
#pragma clang fp contract(off)
    return 1.0f / (1.0f + expf(-v));
}

// ---------------- Decode: 16 lanes per candidate ----------------
// x layout: (16, 3, NY, NX, 85) contiguous. Candidate g = row index.
// Writes conf[g] and class-offset xyxy box[4*g..] to workspace.
template<int NY, int NX>
__global__ __launch_bounds__(256) void decode_kernel(
    const float* __restrict__ x, const float* __restrict__ anch /*6 floats: this level*/,
    float* __restrict__ confW, float* __restrict__ boxW)
{
#pragma clang fp contract(off)
    constexpr int HW = NY * NX;
    constexpr int NPC = 3 * HW;
    constexpr int N = 16 * NPC;
    int t = blockIdx.x * 256 + threadIdx.x;
    int g = t >> 4;
    if (g >= N) return;
    int l16 = t & 15;
    const float* row = x + (long)g * 85;

    // max over 80 class logits, tie -> lowest class index
    float bv = -FLT_MAX; int bc = 0;
#pragma unroll
    for (int j = 0; j < 5; ++j) {
        float v = row[5 + l16 + 16 * j];
        if (v > bv) { bv = v; bc = l16 + 16 * j; }
    }
#pragma unroll
    for (int off = 8; off; off >>= 1) {
        float ov = __shfl_xor(bv, off);
        int   oc = __shfl_xor(bc, off);
        if (ov > bv || (ov == bv && oc < bc)) { bv = ov; bc = oc; }
    }
    if (l16 != 0) return;

    float v0 = row[0], v1 = row[1], v2 = row[2], v3 = row[3], v4 = row[4];
    int i   = g % NPC;
    int a   = i / HW;
    int rem = i - a * HW;
    int gy  = rem / NX;
    int gx  = rem - gy * NX;

    float conf = sigm(bv) * sigm(v4);
    float cx = sigm(v0) * 2.0f + ((float)gx - 0.5f);
    float cy = sigm(v1) * 2.0f + ((float)gy - 0.5f);
    float tw = sigm(v2) * 2.0f, th = sigm(v3) * 2.0f;
    float w = (tw * tw) * anch[a * 2 + 0];
    float h = (th * th) * anch[a * 2 + 1];
    float x1 = cx - w / 2.0f, y1 = cy - h / 2.0f;
    float x2 = cx + w / 2.0f, y2 = cy + h / 2.0f;
    float offc = (float)bc * MAX_WH;   // exact product (j integer)

    confW[g] = conf;
    float4 bb = make_float4(x1 + offc, y1 + offc, x2 + offc, y2 + offc);
    *reinterpret_cast<float4*>(boxW + (long)g * 4) = bb;
}

// ---------------- NMS + gather: one block per (level, image) ----------------
struct LvlParams {
    const float* feat;
    long candOff;   // candidate offset of this level in workspace
    long outOff;    // float offset of this level in d_out
    int npc, ny, nx, C;
};

__global__ __launch_bounds__(512) void nms_gather_kernel(
    const float* __restrict__ confW, const float* __restrict__ boxW,
    float* __restrict__ out, LvlParams p0, LvlParams p1, LvlParams p2)
{
#pragma clang fp contract(off)
    __shared__ float sconf[19200];
    __shared__ float selBox[MAX_DET][4];
    __shared__ int   selIdx[MAX_DET];
    __shared__ int   selValid[MAX_DET];
    __shared__ float rv[8];
    __shared__ int   ri[8];
    __shared__ float bmv;
    __shared__ int   bmi;
    __shared__ int   rejFlag;

    int lvl = blockIdx.x >> 4;
    int b   = blockIdx.x & 15;
    LvlParams p = (lvl == 0) ? p0 : ((lvl == 1) ? p1 : p2);
    const int tid = threadIdx.x;
    const int BT  = blockDim.x;
    const long base = p.candOff + (long)b * p.npc;
    const float* gconf = confW + base;
    const float* gbox  = boxW + base * 4;

    for (int i = tid; i < p.npc; i += BT) sconf[i] = gconf[i];
    if (tid < MAX_DET) selValid[tid] = 0;
    __syncthreads();

    int k = 0;
    while (k < MAX_DET) {
        // ---- block-wide argmax over sconf, tie -> smallest index ----
        float bv = -FLT_MAX; int bi = 0x7FFFFFFF;
        for (int i = tid; i < p.npc; i += BT) {
            float v = sconf[i];
            if (v > bv) { bv = v; bi = i; }
        }
#pragma unroll
        for (int off = 32; off; off >>= 1) {
            float ov = __shfl_down(bv, off);
            int   oi = __shfl_down(bi, off);
            if (ov > bv || (ov == bv && oi < bi)) { bv = ov; bi = oi; }
        }
        if ((tid & 63) == 0) { rv[tid >> 6] = bv; ri[tid >> 6] = bi; }
        __syncthreads();
        if (tid == 0) {
            float mv = rv[0]; int mi = ri[0];
            int nw = BT >> 6;
            for (int w2 = 1; w2 < nw; ++w2)
                if (rv[w2] > mv || (rv[w2] == mv && ri[w2] < mi)) { mv = rv[w2]; mi = ri[w2]; }
            bmv = mv; bmi = mi; rejFlag = 0;
        }
        __syncthreads();
        float mv = bmv; int mi = bmi;
        if (mv < 0.0f) break;   // no valid candidates remain

        // ---- deferred suppression check: IoU vs previously selected ----
        if (tid < k) {
            float cx1 = gbox[(long)mi * 4 + 0], cy1 = gbox[(long)mi * 4 + 1];
            float cx2 = gbox[(long)mi * 4 + 2], cy2 = gbox[(long)mi * 4 + 3];
            float sx1 = selBox[tid][0], sy1 = selBox[tid][1];
            float sx2 = selBox[tid][2], sy2 = selBox[tid][3];
            float ltx = fmaxf(sx1, cx1), lty = fmaxf(sy1, cy1);
            float rbx = fminf(sx2, cx2), rby = fminf(sy2, cy2);
            float ww = fmaxf(rbx - ltx, 0.0f), hh = fmaxf(rby - lty, 0.0f);
            float inter = ww * hh;
            float area1 = (sx2 - sx1) * (sy2 - sy1);
            float area2 = (cx2 - cx1) * (cy2 - cy1);
            float iou = inter / (area1 + area2 - inter);
            if (iou > IOU_THRES) rejFlag = 1;
        }
        __syncthreads();
        int rej = rejFlag;
        if (tid == 0) {
            sconf[mi] = -1.0f;   // examined (selected boxes self-suppress; rejected removed)
            if (!rej) {
                selIdx[k] = mi; selValid[k] = 1;
                selBox[k][0] = gbox[(long)mi * 4 + 0];
                selBox[k][1] = gbox[(long)mi * 4 + 1];
                selBox[k][2] = gbox[(long)mi * 4 + 2];
                selBox[k][3] = gbox[(long)mi * 4 + 3];
            }
        }
        __syncthreads();
        if (!rej) k++;
    }
    __syncthreads();

    // ---- gather features for the 25 output slots ----
    const int hw = p.ny * p.nx;
    for (int k2 = 0; k2 < MAX_DET; ++k2) {
        long obase = p.outOff + ((long)b * MAX_DET + k2) * p.C;
        if (selValid[k2]) {
            int idx = selIdx[k2];
            int rem = idx % hw;          // idx = a*hw + gy*nx + gx
            int gy = rem / p.nx, gx = rem - gy * p.nx;
            const float* f = p.feat + (long)b * p.C * hw + (long)gy * p.nx + gx;
            for (int c = tid; c < p.C; c += BT)
                out[obase + c] = f[(long)c * hw];
        } else {
            for (int c = tid; c < p.C; c += BT)
                out[obase + c] = 0.0f;
        }
    }
}

extern "C" void kernel_launch(void* const* d_in, const int* in_sizes, int n_in,
                              void* d_out, int out_size, void* d_ws, size_t ws_size,
                              hipStream_t stream)
{
    // Map inputs by unique element counts (robust to dict vs signature order).
    const float* xs[3] = {nullptr, nullptr, nullptr};
    const float* fs[3] = {nullptr, nullptr, nullptr};
    const float* anch  = nullptr;
    for (int i = 0; i < n_in; ++i) {
        const float* p = (const float*)d_in[i];
        switch (in_sizes[i]) {
            case 26112000: xs[0] = p; break;   // x0 (16,3,80,80,85)
            case 6528000:  xs[1] = p; break;   // x1 (16,3,40,40,85)
            case 1632000:  xs[2] = p; break;   // x2 (16,3,20,20,85)
            case 13107200: fs[0] = p; break;   // features0 (16,128,80,80)
            case 6553600:  fs[1] = p; break;   // features1 (16,256,40,40)
            case 3276800:  fs[2] = p; break;   // features2 (16,512,20,20)
            case 18:       anch  = p; break;   // anchors (3,3,2)
        }
    }

    float* confW = (float*)d_ws;                          // 403200 floats
    float* boxW  = (float*)((char*)d_ws + 403200L * 4);   // 403200 * 4 floats (16B aligned)

    decode_kernel<80, 80><<<19200, 256, 0, stream>>>(xs[0], anch + 0,  confW + 0,      boxW + 0L);
    decode_kernel<40, 40><<<4800,  256, 0, stream>>>(xs[1], anch + 6,  confW + 307200, boxW + 307200L * 4);
    decode_kernel<20, 20><<<1200,  256, 0, stream>>>(xs[2], anch + 12, confW + 384000, boxW + 384000L * 4);

    LvlParams P0{fs[0], 0L,      0L,      19200, 80, 80, 128};
    LvlParams P1{fs[1], 307200L, 51200L,  4800,  40, 40, 256};
    LvlParams P2{fs[2], 384000L, 153600L, 1200,  20, 20, 512};

    nms_gather_kernel<<<48, 512, 0, stream>>>(confW, boxW, (float*)d_out, P0, P1, P2);
}